// Round 2
// baseline (12512.761 us; speedup 1.0000x reference)
//
#include <hip/hip_runtime.h>

typedef __attribute__((ext_vector_type(8))) short bf16x8;   // 8 bf16 (4 VGPRs)
typedef __attribute__((ext_vector_type(4))) float f32x4;
typedef unsigned short u16;
typedef unsigned long long u64;

#define T_SEQ 512
#define NBLK  192
#define FPAD  16        // ints per flag slot = one 64B line
#define RSLOT 4         // ring depth for h0ring / h1ring / pabuf

__device__ __forceinline__ u16 f2bf(float f) {
  unsigned int u = __float_as_uint(f);
  u += 0x7fffu + ((u >> 16) & 1u);           // RNE
  return (u16)(u >> 16);
}
__device__ __forceinline__ float sigm_(float x) { return 1.f / (1.f + __expf(-x)); }
__device__ __forceinline__ float tanh_(float x) { return 1.f - 2.f / (__expf(2.f * x) + 1.f); }

template <typename T>
__device__ __forceinline__ void st_agent(T* p, T v) {
  __hip_atomic_store(p, v, __ATOMIC_RELAXED, __HIP_MEMORY_SCOPE_AGENT);
}
template <typename T>
__device__ __forceinline__ T ld_agent(const T* p) {
  return __hip_atomic_load(p, __ATOMIC_RELAXED, __HIP_MEMORY_SCOPE_AGENT);
}
__device__ __forceinline__ u64 pack2f(float a, float b) {
  return (u64)__float_as_uint(a) | ((u64)__float_as_uint(b) << 32);
}
__device__ __forceinline__ u64 pack4bf(f32x4 v) {
  return (u64)f2bf(v[0]) | ((u64)f2bf(v[1]) << 16) |
         ((u64)f2bf(v[2]) << 32) | ((u64)f2bf(v[3]) << 48);
}

// ---------- prologue kernels ----------
__global__ void fc_kernel(const float* __restrict__ x, const float* __restrict__ w,
                          const float* __restrict__ bias, float* __restrict__ z) {
  int idx = blockIdx.x * 256 + threadIdx.x;    // 131072 = 128*1024
  int b = idx >> 10, i = idx & 1023;
  const float* xr = x + b * 256;
  const float* wr = w + i * 256;
  float acc = bias[i];
  #pragma unroll 4
  for (int o = 0; o < 256; ++o) acc += xr[o] * wr[o];
  z[idx] = acc;
}

__global__ void gx0_kernel(const float* __restrict__ z, const float* __restrict__ Wih0,
                           const float* __restrict__ bih, const float* __restrict__ bhh,
                           float* __restrict__ gx0) {
  int idx = blockIdx.x * 256 + threadIdx.x;    // 524288 = 128*4096
  int b = idx >> 12, j = idx & 4095;
  const float* zr = z + b * 1024;
  const float* wr = Wih0 + (size_t)j * 1024;
  float acc = bih[j] + bhh[j];
  #pragma unroll 4
  for (int k = 0; k < 1024; ++k) acc += zr[k] * wr[k];
  gx0[idx] = acc;
}

// ---------- persistent fused 2-layer LSTM, dataflow-synchronized ----------
// 192 blocks x 512 threads, 1 block/CU. Roles:
//   role0: layer0 recurrence (h0(t-1) -> h0(t))
//   role1: layer1 input-side (h0(t) -> pa(t), point-to-point to role2 partner)
//   role2: layer1 recurrence + pointwise + out (pa(t), h1(t-1) -> h1(t))
// vs previous version (three changes):
// 1. B-IN-REGISTERS: W fragments for gates 0,1 preloaded into 128 VGPRs once
//    (W is constant across all 512 steps). LDS only serves gates 2,3 ->
//    per-step LDS B-read traffic halves (512KB -> 256KB/block), wlds 128->64KB.
// 2. PER-WAVE POLLING: no front __syncthreads. Each wave polls only its own
//    32 K-producers (its K-half), fences (per-wave acquire = L1 inv), and
//    starts its A-loads immediately. Cross-step LDS reuse safety:
//      red write(t, w>=4) vs red read(t-1, w<4): separated by stage-sync +
//        drain-sync of step t-1 (block-wide).  [role1: by drain-sync]
//      stage write(t, w<4) vs stage read(t-1, all): separated by drain-sync.
//    Backpressure polls moved next to the stores they protect; role2's
//    pa-wait moved after the MFMA loop (off the h1-recurrence front edge).
// 3. MERGED REDUCE: freed LDS lets red hold acc0+acc1 together (stride 44
//    words -> conflict-free) -> one write/read round, 2 fewer syncthreads.
//    role2's out store moved after flag publish (it has no consumer).
// Flags are slot-less monotone ints (value = t+1), one 64B line per producer.
__global__ __launch_bounds__(512, 2)
void lstm_persist(const float* __restrict__ Whh0, const float* __restrict__ Wih1,
                  const float* __restrict__ Whh1, const float* __restrict__ gx0,
                  const float* __restrict__ bih1, const float* __restrict__ bhh1,
                  u16* __restrict__ h0ring, u16* __restrict__ h1ring,
                  float* __restrict__ pabuf, float* __restrict__ out,
                  int* __restrict__ h0flag, int* __restrict__ paflag,
                  int* __restrict__ h1flag) {
  __shared__ __align__(16) u16 wlds2[2][2048][8];      // 64 KiB (gates 2,3)
  __shared__ __align__(16) float red[4][64][44];       // 44 KiB (acc0+acc1 merged)
  __shared__ __align__(16) float stage[128][20];       // 10 KiB (h staging)

  const int bid = blockIdx.x;
  const int role = bid >> 6;
  const int cslice = bid & 63;
  const int cb = cslice * 16;        // h-col base
  const int tid = threadIdx.x;
  const int w = tid >> 6;            // wave 0..7
  const int lane = tid & 63;
  const int l15 = lane & 15;
  const int q = lane >> 4;
  const int Mg = w & 3;              // M-group: batches Mg*32..+32
  const int kh = w >> 2;             // K-half

  const float* Wsrc = (role == 0) ? Whh0 : (role == 1) ? Wih1 : Whh1;

  // ---- stage W gates 2,3 fp32 -> bf16 -> LDS (once) ----
  {
    const int r = tid >> 4;          // 0..31
    const int g2 = r >> 4, n = r & 15;
    const int k0 = (tid & 15) * 64;
    const float* src = Wsrc + (((size_t)((2 + g2) * 1024 + cb + n)) << 10) + k0;
    for (int k = 0; k < 64; k += 4) {
      float4 v = *(const float4*)(src + k);
      ushort4 o;
      o.x = f2bf(v.x); o.y = f2bf(v.y); o.z = f2bf(v.z); o.w = f2bf(v.w);
      const int kk = k0 + k;
      *(ushort4*)&wlds2[g2][((kk >> 3) << 4) + n][kk & 7] = o;
    }
  }

  // ---- preload W gates 0,1 fragments into registers (once) ----
  bf16x8 breg[2][16];
  {
    #pragma unroll
    for (int g = 0; g < 2; ++g) {
      const float* wrow = Wsrc + (((size_t)(g * 1024 + cb + l15)) << 10) + kh * 512 + q * 8;
      #pragma unroll
      for (int kk = 0; kk < 16; ++kk) {
        float4 v0 = *(const float4*)(wrow + kk * 32);
        float4 v1 = *(const float4*)(wrow + kk * 32 + 4);
        union { bf16x8 v; u16 u[8]; } tmp;
        tmp.u[0] = f2bf(v0.x); tmp.u[1] = f2bf(v0.y);
        tmp.u[2] = f2bf(v0.z); tmp.u[3] = f2bf(v0.w);
        tmp.u[4] = f2bf(v1.x); tmp.u[5] = f2bf(v1.y);
        tmp.u[6] = f2bf(v1.z); tmp.u[7] = f2bf(v1.w);
        breg[g][kk] = tmp.v;
      }
    }
  }

  // ---- per-thread persistent state ----
  float c_st[2][4];
  #pragma unroll
  for (int mt = 0; mt < 2; ++mt)
    #pragma unroll
    for (int r = 0; r < 4; ++r) c_st[mt][r] = 0.f;

  float gx[2][4][4];                 // role0: gx0 base slice
  float b1[4];                       // role2: bias
  if (role == 0 && w < 4) {
    #pragma unroll
    for (int mt = 0; mt < 2; ++mt)
      #pragma unroll
      for (int g = 0; g < 4; ++g)
        #pragma unroll
        for (int r = 0; r < 4; ++r)
          gx[mt][g][r] = gx0[(size_t)(w * 32 + mt * 16 + q * 4 + r) * 4096 + g * 1024 + cb + l15];
  }
  if (role == 2 && w < 4) {
    #pragma unroll
    for (int g = 0; g < 4; ++g)
      b1[g] = bih1[g * 1024 + cb + l15] + bhh1[g * 1024 + cb + l15];
  }
  __syncthreads();                   // wlds2 ready

  const size_t HSLOT = (size_t)128 * 1024;   // elems per h ring slot

  for (int t = 0; t < T_SEQ; ++t) {
    const int sA = (t + 3) & 3;      // slot holding h(t-1)
    const int sW = t & 3;            // slot this step writes

    // ---- per-wave dataflow wait: only THIS wave's 32 K-producers ----
    // role0: h0(t-1) (flag>=t). role1: h0(t) (flag>=t+1). role2: h1(t-1).
    // (role2's h1 slot-overwrite safety is subsumed: peers' flag>=t >= t-3.)
    {
      const int pl = kh * 32 + (lane & 31);
      const int* fl = (role == 2) ? h1flag : h0flag;
      const int thr = (role == 1) ? t + 1 : t;
      bool ok;
      do {
        int f = ld_agent(fl + pl * FPAD);
        ok = __all(f >= thr);
        if (!ok) __builtin_amdgcn_s_sleep(1);
      } while (!ok);
      __builtin_amdgcn_fence(__ATOMIC_ACQUIRE, "agent");   // per-wave L1 inv
    }

    const u16* A = (role == 0) ? h0ring + (size_t)sA * HSLOT
                 : (role == 1) ? h0ring + (size_t)sW * HSLOT
                               : h1ring + (size_t)sA * HSLOT;

    const int kbase = kh * 512;
    const u16* Ap = A + (((size_t)(Mg * 32 + l15)) << 10) + kbase + q * 8;
    const int cellbase = ((kbase >> 3) + q) * 16 + l15;   // + kk*64

    f32x4 acc0[4] = {{0.f,0.f,0.f,0.f},{0.f,0.f,0.f,0.f},{0.f,0.f,0.f,0.f},{0.f,0.f,0.f,0.f}};
    f32x4 acc1[4] = {{0.f,0.f,0.f,0.f},{0.f,0.f,0.f,0.f},{0.f,0.f,0.f,0.f},{0.f,0.f,0.f,0.f}};

    #pragma unroll
    for (int kk = 0; kk < 16; ++kk) {
      bf16x8 a0 = *(const bf16x8*)(Ap + kk * 32);
      bf16x8 a1 = *(const bf16x8*)(Ap + (16 << 10) + kk * 32);
      acc0[0] = __builtin_amdgcn_mfma_f32_16x16x32_bf16(a0, breg[0][kk], acc0[0], 0, 0, 0);
      acc1[0] = __builtin_amdgcn_mfma_f32_16x16x32_bf16(a1, breg[0][kk], acc1[0], 0, 0, 0);
      acc0[1] = __builtin_amdgcn_mfma_f32_16x16x32_bf16(a0, breg[1][kk], acc0[1], 0, 0, 0);
      acc1[1] = __builtin_amdgcn_mfma_f32_16x16x32_bf16(a1, breg[1][kk], acc1[1], 0, 0, 0);
      bf16x8 b2 = *(const bf16x8*)&wlds2[0][cellbase + kk * 64][0];
      acc0[2] = __builtin_amdgcn_mfma_f32_16x16x32_bf16(a0, b2, acc0[2], 0, 0, 0);
      acc1[2] = __builtin_amdgcn_mfma_f32_16x16x32_bf16(a1, b2, acc1[2], 0, 0, 0);
      bf16x8 b3 = *(const bf16x8*)&wlds2[1][cellbase + kk * 64][0];
      acc0[3] = __builtin_amdgcn_mfma_f32_16x16x32_bf16(a0, b3, acc0[3], 0, 0, 0);
      acc1[3] = __builtin_amdgcn_mfma_f32_16x16x32_bf16(a1, b3, acc1[3], 0, 0, 0);
    }

    // role2: pa(t) wait (moved off the front edge) + early u64 loads;
    // the LDS reduction below hides the load latency.
    u64 pa64[16];
    const float* pr = pabuf + (size_t)sW * 524288 + (size_t)(cslice * 4 + w) * 2048;
    if (role == 2 && w < 4) {
      while (ld_agent(paflag + cslice * FPAD) < t + 1) __builtin_amdgcn_s_sleep(1);
      #pragma unroll
      for (int j = 0; j < 8; ++j) {
        pa64[j * 2]     = ld_agent((const u64*)pr + j * 128 + lane * 2);
        pa64[j * 2 + 1] = ld_agent((const u64*)pr + j * 128 + lane * 2 + 1);
      }
    }

    // ---- K-half reduction via LDS (single merged round) ----
    if (w >= 4) {
      #pragma unroll
      for (int g = 0; g < 4; ++g) {
        *(f32x4*)&red[w - 4][lane][g * 4]      = acc0[g];
        *(f32x4*)&red[w - 4][lane][16 + g * 4] = acc1[g];
      }
    }
    __syncthreads();                 // sync#1: red ready
    if (w < 4) {
      #pragma unroll
      for (int g = 0; g < 4; ++g) {
        acc0[g] += *(const f32x4*)&red[w][lane][g * 4];
        acc1[g] += *(const f32x4*)&red[w][lane][16 + g * 4];
      }

      if (role == 1) {
        // backpressure: partner role2 published h1(t-4) => pabuf slot sW free
        while (ld_agent(h1flag + cslice * FPAD) < t - 3) __builtin_amdgcn_s_sleep(1);
        float* pw = pabuf + (size_t)sW * 524288 + (size_t)(cslice * 4 + w) * 2048;
        #pragma unroll
        for (int g = 0; g < 4; ++g) {
          st_agent((u64*)pw + g * 128 + lane * 2,           pack2f(acc0[g][0], acc0[g][1]));
          st_agent((u64*)pw + g * 128 + lane * 2 + 1,       pack2f(acc0[g][2], acc0[g][3]));
          st_agent((u64*)pw + (4 + g) * 128 + lane * 2,     pack2f(acc1[g][0], acc1[g][1]));
          st_agent((u64*)pw + (4 + g) * 128 + lane * 2 + 1, pack2f(acc1[g][2], acc1[g][3]));
        }
      } else {
        #pragma unroll
        for (int mt = 0; mt < 2; ++mt) {
          #pragma unroll
          for (int r = 0; r < 4; ++r) {
            float xi, xf, xg, xo;
            f32x4* a = mt ? acc1 : acc0;
            if (role == 0) {
              xi = a[0][r] + gx[mt][0][r];
              xf = a[1][r] + gx[mt][1][r];
              xg = a[2][r] + gx[mt][2][r];
              xo = a[3][r] + gx[mt][3][r];
            } else {
              const int h2 = r >> 1, lo = r & 1;
              auto up = [&](int j) {
                u64 v = pa64[j * 2 + h2];
                return __uint_as_float(lo ? (unsigned)(v >> 32) : (unsigned)v);
              };
              xi = a[0][r] + up(mt * 4 + 0) + b1[0];
              xf = a[1][r] + up(mt * 4 + 1) + b1[1];
              xg = a[2][r] + up(mt * 4 + 2) + b1[2];
              xo = a[3][r] + up(mt * 4 + 3) + b1[3];
            }
            float i_ = sigm_(xi), f_ = sigm_(xf), g_ = tanh_(xg), o_ = sigm_(xo);
            float cn = f_ * c_st[mt][r] + i_ * g_;
            c_st[mt][r] = cn;
            float h = o_ * tanh_(cn);
            stage[w * 32 + mt * 16 + q * 4 + r][l15] = h;   // f32 h to LDS stage
          }
        }
      }
    }

    if (role != 1) {
      __syncthreads();                       // sync#2: stage[] ready
      if (role == 0) {
        // backpressure: all 64 role1 blocks read h0(t-4) => slot sW free
        bool ok;
        do {
          int f = ld_agent(paflag + lane * FPAD);
          ok = __all(f >= t - 3);
          if (!ok) __builtin_amdgcn_s_sleep(1);
        } while (!ok);
      }
      const int row = tid >> 2, qt = tid & 3;
      f32x4 v = *(const f32x4*)&stage[row][qt * 4];
      u64 pk = pack4bf(v);
      if (role == 0) {
        st_agent((u64*)(h0ring + (size_t)sW * HSLOT + ((size_t)row << 10) + cb) + qt, pk);
      } else {
        st_agent((u64*)(h1ring + (size_t)sW * HSLOT + ((size_t)row << 10) + cb) + qt, pk);
      }
      __syncthreads();                       // sync#3: per-wave vmcnt drain
      if (tid == 0) {
        if (role == 0) st_agent(h0flag + cslice * FPAD, t + 1);
        else           st_agent(h1flag + cslice * FPAD, t + 1);
      }
      if (role == 2) {
        // out has NO cross-block reader: plain cached store, after flag
        *(f32x4*)(out + (size_t)row * ((size_t)T_SEQ * 1024) + (size_t)t * 1024 + cb + qt * 4) = v;
      }
    } else {
      __syncthreads();                       // sync#2: pa store drain
      if (tid == 0) st_agent(paflag + cslice * FPAD, t + 1);
    }
  }
}

// ---------- launch ----------
extern "C" void kernel_launch(void* const* d_in, const int* in_sizes, int n_in,
                              void* d_out, int out_size, void* d_ws, size_t ws_size,
                              hipStream_t stream) {
  (void)in_sizes; (void)n_in; (void)out_size; (void)ws_size;
  const float* x    = (const float*)d_in[0];
  const float* fc_w = (const float*)d_in[1];
  const float* fc_b = (const float*)d_in[2];
  const float* Wih0 = (const float*)d_in[3];
  const float* Whh0 = (const float*)d_in[4];
  const float* bih0 = (const float*)d_in[5];
  const float* bhh0 = (const float*)d_in[6];
  const float* Wih1 = (const float*)d_in[7];
  const float* Whh1 = (const float*)d_in[8];
  const float* bih1 = (const float*)d_in[9];
  const float* bhh1 = (const float*)d_in[10];
  float* out = (float*)d_out;

  char* ws = (char*)d_ws;
  size_t off = 0;
  auto alloc = [&](size_t bytes) -> void* {
    void* p = ws + off;
    off += (bytes + 255) & ~(size_t)255;
    return p;
  };
  float* z      = (float*)alloc((size_t)128 * 1024 * 4);
  float* gx0    = (float*)alloc((size_t)128 * 4096 * 4);
  u16*   h0ring = (u16*)alloc((size_t)RSLOT * 128 * 1024 * 2);
  u16*   h1ring = (u16*)alloc((size_t)RSLOT * 128 * 1024 * 2);
  float* pabuf  = (float*)alloc((size_t)RSLOT * 524288 * 4);
  int*   h0flag = (int*)alloc((size_t)64 * FPAD * 4);
  int*   paflag = (int*)alloc((size_t)64 * FPAD * 4);
  int*   h1flag = (int*)alloc((size_t)64 * FPAD * 4);

  hipMemsetAsync(h0ring, 0, (size_t)RSLOT * 128 * 1024 * 2, stream);
  hipMemsetAsync(h1ring, 0, (size_t)RSLOT * 128 * 1024 * 2, stream);
  hipMemsetAsync(h0flag, 0, (size_t)64 * FPAD * 4, stream);
  hipMemsetAsync(paflag, 0, (size_t)64 * FPAD * 4, stream);
  hipMemsetAsync(h1flag, 0, (size_t)64 * FPAD * 4, stream);

  fc_kernel<<<512, 256, 0, stream>>>(x, fc_w, fc_b, z);
  gx0_kernel<<<2048, 256, 0, stream>>>(z, Wih0, bih0, bhh0, gx0);

  lstm_persist<<<NBLK, 512, 0, stream>>>(Whh0, Wih1, Whh1, gx0, bih1, bhh1,
                                         h0ring, h1ring, pabuf, out,
                                         h0flag, paflag, h1flag);
}